// Round 3
// baseline (117.682 us; speedup 1.0000x reference)
//
#include <hip/hip_runtime.h>

// Involution2d, 2-kernel (R15: 64-reg occupancy + halo-direct-from-global).
// K0: x f32 -> xp8 bf16 in PADDED layout [b][oct=ch/8][row 0..69][col 0..69][8ch],
//     image at rows/cols 3..66, borders zeroed (re-zeroed every iter since the
//     harness poisons the workspace). w -> bf16.
// K1 per block (b, g, 4-row x 64-px tile), 512 threads / 8 waves:
//   GEMM: wave owns 4 m-tiles x 2 n-tiles; SINGLE-buffered frags, s-base +
//   32-bit voffset addressing -> total regs (VGPR+AGPR) <= 64 so 8 waves/SIMD.
//   __launch_bounds__(512,8) forces the 64-reg tier: 4 blocks/CU resident,
//   32 waves/CU, grid = 1024 = exactly 4/CU -> ONE balanced round. Latency
//   hiding via TLP (32 waves), not per-wave pipelining.
//   Halo: NO LDS staging -- apply reads taps directly from padded xp8 (L1/L2
//   resident, 1KB/wave coalesced, 15/16 L1-line reuse across kw). LDS = kern2
//   only (28,672 B). ONE barrier.
//   Apply: tid<256 -> oct 2g, tid>=256 -> oct 2g+1; hi channel uses the raw
//   dword as f32 (low 16 bits sub-bf16 noise, <=0.4% rel).

#define B_   4
#define C_   256
#define G_   16
#define KK_  49
#define KS_  7
#define PD_  3

#define PROW  70
#define POCT  (PROW*PROW)                 // 4900 positions per (b,oct)
#define XP8_BYTES (B_*32*POCT*16)         // 10,035,200 (mult of 256)
#define WBF_OFF   XP8_BYTES

#define SKW   28            // kern2 row stride, dwords (=56 bf16, 49 used)

typedef __attribute__((ext_vector_type(8))) short bf16x8;
typedef __attribute__((ext_vector_type(4))) float f32x4;
typedef unsigned short ushort_t;

__device__ inline unsigned f2bf(float f) {            // RNE fp32->bf16
    unsigned u = __float_as_uint(f);
    u += 0x7FFF + ((u >> 16) & 1);
    return u >> 16;
}

// ---------------- K0: x -> padded xp8 (channel-packed bf16); w -> bf16 ----------------
__global__ __launch_bounds__(256)
void cvt_xp8(const float* __restrict__ x, const float* __restrict__ wk,
             ushort_t* __restrict__ xp8, unsigned* __restrict__ wbf) {
    const int t = threadIdx.x;
    if (blockIdx.x == 64) {   // W convert: 100352 f32 pairs, 16 slices
        const int slice = blockIdx.z * 4 + blockIdx.y;
        const float2* wk2 = (const float2*)wk;
        const int base = slice * 6272;
        for (int k = t; k < 6272; k += 256) {
            float2 v = wk2[base + k];
            wbf[base + k] = f2bf(v.x) | (f2bf(v.y) << 16);
        }
        return;
    }
    if (blockIdx.x == 65) {   // zero pad borders: 804 positions x 8 octs
        const int b  = blockIdx.z;
        const int o0 = blockIdx.y * 8;
        const uint4 z = make_uint4(0u, 0u, 0u, 0u);
        #pragma unroll
        for (int o = 0; o < 8; ++o) {
            ushort_t* base = xp8 + (size_t)((b << 5) + o0 + o) * POCT * 8;
            for (int e = t; e < 804; e += 256) {
                int row, col;
                if (e < 420) {                       // full rows 0-2, 67-69
                    row = e / 70; col = e - row * 70;
                    if (row >= 3) row += 64;
                } else {                             // rows 3..66, 6 border cols
                    int f = e - 420;
                    row = 3 + f / 6;
                    int m = f - (f / 6) * 6;
                    col = (m < 3) ? m : 64 + m;
                }
                *(uint4*)(base + (row * PROW + col) * 8) = z;
            }
        }
        return;
    }
    __shared__ float tile[64][65];
    const int p0 = blockIdx.x * 64;       // 64 px = image row blockIdx.x
    const int c0 = blockIdx.y * 64;       // 8 octs per slice
    const int b  = blockIdx.z;
    const int px_r = t & 63;
    #pragma unroll
    for (int i = 0; i < 16; ++i) {
        int ch = (t >> 6) + i * 4;
        tile[ch][px_r] = x[((size_t)(b * C_ + c0 + ch) << 12) + p0 + px_r];
    }
    __syncthreads();
    const int px = t & 63;
    const int ob = t >> 6;                // 0..3
    #pragma unroll
    for (int jj = 0; jj < 2; ++jj) {
        const int j = ob + jj * 4;        // oct within slice, 0..7
        unsigned u[4];
        #pragma unroll
        for (int k2 = 0; k2 < 4; ++k2) {
            float a0 = tile[j * 8 + 2 * k2][px];
            float a1 = tile[j * 8 + 2 * k2 + 1][px];
            u[k2] = f2bf(a0) | (f2bf(a1) << 16);
        }
        ushort_t* dst = xp8 + ((size_t)((b << 5) + (c0 >> 3) + j) * POCT
                               + (blockIdx.x + 3) * PROW + 3 + px) * 8;
        *(uint4*)dst = make_uint4(u[0], u[1], u[2], u[3]);
    }
}

// ---------------- K1: fused GEMM + apply ----------------
__global__ __launch_bounds__(512, 8)
void inv_fused(const ushort_t* __restrict__ xp8,
               const ushort_t* __restrict__ wbf,
               const float* __restrict__ bk,
               float* __restrict__ out) {
    __shared__ unsigned kern2[256 * SKW];     // 28,672 B  [pixel][28 dw]

    const int bid  = blockIdx.x;
    const int g    = bid >> 6;
    const int b    = (bid >> 4) & 3;
    const int tile = bid & 15;
    const int gy0  = tile * 4;
    const int p0   = tile * 256;

    const int tid  = threadIdx.x;
    const int wv   = tid >> 6;                // 0..7
    const int ln15 = tid & 15;
    const int quad = (tid & 63) >> 4;

    // ---- GEMM: wave wv owns n-cols p0+wv*32 (2 n-tiles) x 4 m-tiles ----
    f32x4 acc[8];
    #pragma unroll
    for (int i = 0; i < 8; ++i) acc[i] = (f32x4){0.f, 0.f, 0.f, 0.f};

    const char* bbase = (const char*)xp8 + (size_t)b * 32 * POCT * 16;
    const char* abase = (const char*)wbf + (size_t)g * KK_ * 512;

    int vb0, vb1;
    {
        int gi0 = p0 + wv * 32 + ln15;            // nt=0 pixel index
        int gi1 = gi0 + 16;                        // nt=1
        vb0 = (quad * POCT + ((gi0 >> 6) + 3) * PROW + 3 + (gi0 & 63)) * 16;
        vb1 = (quad * POCT + ((gi1 >> 6) + 3) * PROW + 3 + (gi1 & 63)) * 16;
    }
    int va  = ln15 * 512 + quad * 16;         // mt 0..2: + mt*8192 via s-base
    int va3 = 48 * 512 + quad * 16;           // mt 3: row clamped to 48

    #pragma unroll
    for (int k = 0; k < 8; ++k) {
        bf16x8 af0 = *(const bf16x8*)(abase + va);
        bf16x8 af1 = *(const bf16x8*)(abase + 8192 + va);
        bf16x8 af2 = *(const bf16x8*)(abase + 16384 + va);
        bf16x8 af3 = *(const bf16x8*)(abase + va3);
        bf16x8 bf0 = *(const bf16x8*)(bbase + vb0);
        bf16x8 bf1 = *(const bf16x8*)(bbase + vb1);
        acc[0] = __builtin_amdgcn_mfma_f32_16x16x32_bf16(af0, bf0, acc[0], 0, 0, 0);
        acc[1] = __builtin_amdgcn_mfma_f32_16x16x32_bf16(af0, bf1, acc[1], 0, 0, 0);
        acc[2] = __builtin_amdgcn_mfma_f32_16x16x32_bf16(af1, bf0, acc[2], 0, 0, 0);
        acc[3] = __builtin_amdgcn_mfma_f32_16x16x32_bf16(af1, bf1, acc[3], 0, 0, 0);
        acc[4] = __builtin_amdgcn_mfma_f32_16x16x32_bf16(af2, bf0, acc[4], 0, 0, 0);
        acc[5] = __builtin_amdgcn_mfma_f32_16x16x32_bf16(af2, bf1, acc[5], 0, 0, 0);
        acc[6] = __builtin_amdgcn_mfma_f32_16x16x32_bf16(af3, bf0, acc[6], 0, 0, 0);
        acc[7] = __builtin_amdgcn_mfma_f32_16x16x32_bf16(af3, bf1, acc[7], 0, 0, 0);
        va  += 64;  va3 += 64;                 // +32 channels
        vb0 += 4 * POCT * 16; vb1 += 4 * POCT * 16;   // +4 octs
    }

    // ---- epilogue: D[m=quad*4+r][n=ln15] -> kern2[pixel][m] bf16 ----
    #pragma unroll
    for (int mt = 0; mt < 3; ++mt) {                      // m <= 47
        const int m0 = mt * 16 + quad * 4;
        const float b0 = bk[g * KK_ + m0],     b1 = bk[g * KK_ + m0 + 1];
        const float b2 = bk[g * KK_ + m0 + 2], b3 = bk[g * KK_ + m0 + 3];
        #pragma unroll
        for (int nt = 0; nt < 2; ++nt) {
            const int p = wv * 32 + nt * 16 + ln15;
            uint2 d;
            d.x = f2bf(acc[mt * 2 + nt][0] + b0) | (f2bf(acc[mt * 2 + nt][1] + b1) << 16);
            d.y = f2bf(acc[mt * 2 + nt][2] + b2) | (f2bf(acc[mt * 2 + nt][3] + b3) << 16);
            *(uint2*)&kern2[p * SKW + mt * 8 + quad * 2] = d;
        }
    }
    if (quad == 0) {                                      // mt=3: only m=48 valid
        const float b48 = bk[g * KK_ + 48];
        #pragma unroll
        for (int nt = 0; nt < 2; ++nt) {
            const int p = wv * 32 + nt * 16 + ln15;
            kern2[p * SKW + 24] = f2bf(acc[6 + nt][0] + b48);   // lo=m48
        }
    }

    __syncthreads();   // the only barrier: kern2 complete

    // ---- my pixel's 49 kern values: 7x ds_read_b128, kept packed ----
    const int pix = tid & 255;
    const int ho  = tid >> 8;
    unsigned kd[28];
    {
        const uint4* kr = (const uint4*)&kern2[pix * SKW];
        #pragma unroll
        for (int q = 0; q < 7; ++q) {
            uint4 h = kr[q];
            kd[4*q] = h.x; kd[4*q+1] = h.y; kd[4*q+2] = h.z; kd[4*q+3] = h.w;
        }
    }

    // ---- apply: halo taps direct from padded xp8 (global, L1/L2-hot) ----
    const int py = pix >> 6, px = pix & 63;
    int vh = ((2 * g + ho) * POCT + (gy0 + py) * PROW + px) * 16;

    float a[8];
    #pragma unroll
    for (int q = 0; q < 8; ++q) a[q] = 0.f;
    #pragma unroll
    for (int kh = 0; kh < KS_; ++kh) {
        #pragma unroll
        for (int kw = 0; kw < KS_; ++kw) {
            uint4 hv = *(const uint4*)(bbase + vh + kw * 16);
            const int t49 = kh * KS_ + kw;
            unsigned d = kd[t49 >> 1];
            float kk = __uint_as_float((t49 & 1) ? (d & 0xffff0000u) : (d << 16));
            a[0] = fmaf(__uint_as_float(hv.x << 16), kk, a[0]);
            a[1] = fmaf(__uint_as_float(hv.x),       kk, a[1]);
            a[2] = fmaf(__uint_as_float(hv.y << 16), kk, a[2]);
            a[3] = fmaf(__uint_as_float(hv.y),       kk, a[3]);
            a[4] = fmaf(__uint_as_float(hv.z << 16), kk, a[4]);
            a[5] = fmaf(__uint_as_float(hv.z),       kk, a[5]);
            a[6] = fmaf(__uint_as_float(hv.w << 16), kk, a[6]);
            a[7] = fmaf(__uint_as_float(hv.w),       kk, a[7]);
        }
        vh += PROW * 16;
    }
    const size_t o = ((size_t)(b * C_ + g * 16 + ho * 8) << 12) + p0 + pix;
    #pragma unroll
    for (int q = 0; q < 8; ++q)
        out[o + ((size_t)q << 12)] = a[q];
}

extern "C" void kernel_launch(void* const* d_in, const int* in_sizes, int n_in,
                              void* d_out, int out_size, void* d_ws, size_t ws_size,
                              hipStream_t stream) {
    const float* x  = (const float*)d_in[0];
    const float* wk = (const float*)d_in[1];
    const float* bk = (const float*)d_in[2];
    float* o = (float*)d_out;

    ushort_t* xp8 = (ushort_t*)d_ws;
    unsigned* wbf = (unsigned*)((char*)d_ws + WBF_OFF);

    cvt_xp8<<<dim3(66, 4, B_), dim3(256), 0, stream>>>(x, wk, xp8, wbf);
    inv_fused<<<dim3(1024), dim3(512), 0, stream>>>(
        xp8, (const ushort_t*)wbf, bk, o);
}

// Round 5
// 114.013 us; speedup vs baseline: 1.0322x; 1.0322x over previous
//
#include <hip/hip_runtime.h>

// Involution2d, 2-kernel (R16: LDS-reuse halo + transposed kernq + aligned K0).
// K0: x f32 -> xp8 bf16 padded [b][oct][row 0..69][col 0..71][8ch], PROW=72 so
//     rows are 1152B = 9x128B aligned; every store is a full contiguous row
//     (pad cols/rows written as zeros inline). w -> bf16.
// K1 per block (b, g, 4-row x 64-px tile), 512 threads / 8 waves, <=64 regs:
//   GEMM: single-buffered frags, s-base + voffset (R15 structure, 8 waves/SIMD).
//   kern stored TRANSPOSED in LDS: kernq[q=0..6][pixel][16B] -> both the
//   epilogue uint2 writes and the 7 per-thread b128 reads are conflict-free
//   (old [pix][28dw] layout was an 8-way alias; 262K conflicts).
//   LDS REUSE: after kv is pulled to regs (barrier), the SAME 28,672B buffer
//   holds the halo (22.4KB, both octs). Halo global loads are branch-free
//   (padding!) and issued before the epilogue. 3 barriers.
//   Apply: tid<256 -> oct 2g, tid>=256 -> oct 2g+1; taps via ds_read_b128
//   (contiguous across lanes, conflict-free); hi channel uses the raw dword
//   as f32 (low 16 bits sub-bf16 noise, <=0.4% rel).
// LDS 28,672 B; <=64 regs -> 4 blocks/CU x 8 waves = 32 waves/CU, grid 1024
// = exactly 4/CU -> one balanced round.
// [R17: resubmit unchanged — R16 bench was a GPUAcquisitionTimeout, no data.]

#define B_   4
#define C_   256
#define G_   16
#define KK_  49
#define KS_  7
#define PD_  3

#define PROW  72
#define POCT  (70*PROW)                   // 5040 positions per (b,oct)
#define XP8_BYTES (B_*32*POCT*16)         // 10,321,920 (mult of 256)
#define WBF_OFF   XP8_BYTES

typedef __attribute__((ext_vector_type(8))) short bf16x8;
typedef __attribute__((ext_vector_type(4))) float f32x4;
typedef unsigned short ushort_t;

__device__ inline unsigned f2bf(float f) {            // RNE fp32->bf16
    unsigned u = __float_as_uint(f);
    u += 0x7FFF + ((u >> 16) & 1);
    return u >> 16;
}

// ---------------- K0: x -> padded xp8 (channel-packed bf16); w -> bf16 ----------------
__global__ __launch_bounds__(256)
void cvt_xp8(const float* __restrict__ x, const float* __restrict__ wk,
             ushort_t* __restrict__ xp8, unsigned* __restrict__ wbf) {
    const int t = threadIdx.x;
    if (blockIdx.x == 64) {   // W convert: 100352 f32 pairs, 16 slices
        const int slice = blockIdx.z * 4 + blockIdx.y;
        const float2* wk2 = (const float2*)wk;
        const int base = slice * 6272;
        for (int k = t; k < 6272; k += 256) {
            float2 v = wk2[base + k];
            wbf[base + k] = f2bf(v.x) | (f2bf(v.y) << 16);
        }
        return;
    }
    if (blockIdx.x == 65) {   // zero pad rows {0,1,2,67,68,69} x 72 cols, 8 octs
        const int b  = blockIdx.z;
        const int o0 = blockIdx.y * 8;
        const uint4 z = make_uint4(0u, 0u, 0u, 0u);
        for (int e = t; e < 6 * PROW * 8; e += 256) {     // 3456
            const int o = e / (6 * PROW);
            const int f = e - o * (6 * PROW);
            const int r = f / PROW;
            const int c = f - r * PROW;
            const int row = (r < 3) ? r : 64 + r;         // 0,1,2,67,68,69
            *(uint4*)(xp8 + ((size_t)((b << 5) + o0 + o) * POCT + row * PROW + c) * 8) = z;
        }
        return;
    }
    __shared__ float tile[64][65];
    const int c0 = blockIdx.y * 64;       // 8 octs per slice
    const int b  = blockIdx.z;
    const int px_r = t & 63;
    #pragma unroll
    for (int i = 0; i < 16; ++i) {
        int ch = (t >> 6) + i * 4;
        tile[ch][px_r] = x[((size_t)(b * C_ + c0 + ch) << 12) + blockIdx.x * 64 + px_r];
    }
    __syncthreads();
    const int lane = t & 63;
    const int ob = t >> 6;                // 0..3
    #pragma unroll
    for (int jj = 0; jj < 2; ++jj) {
        const int j = ob + jj * 4;        // oct within slice, 0..7
        ushort_t* rowbase = xp8 + ((size_t)((b << 5) + (c0 >> 3) + j) * POCT
                                   + (blockIdx.x + 3) * PROW) * 8;
        #pragma unroll
        for (int cc = 0; cc < 2; ++cc) {
            const int col = lane + cc * 64;
            if (col < PROW) {
                uint4 v = make_uint4(0u, 0u, 0u, 0u);
                if (col >= 3 && col < 67) {
                    const int p = col - 3;
                    unsigned u[4];
                    #pragma unroll
                    for (int k2 = 0; k2 < 4; ++k2) {
                        float a0 = tile[j * 8 + 2 * k2][p];
                        float a1 = tile[j * 8 + 2 * k2 + 1][p];
                        u[k2] = f2bf(a0) | (f2bf(a1) << 16);
                    }
                    v = make_uint4(u[0], u[1], u[2], u[3]);
                }
                *(uint4*)(rowbase + col * 8) = v;   // full aligned 1152B row
            }
        }
    }
}

// ---------------- K1: fused GEMM + apply ----------------
__global__ __launch_bounds__(512, 8)
void inv_fused(const ushort_t* __restrict__ xp8,
               const ushort_t* __restrict__ wbf,
               const float* __restrict__ bk,
               float* __restrict__ out) {
    __shared__ unsigned lds[7168];   // 28,672 B: kernq[7][256][4dw], then halo[1400][4dw]

    const int bid  = blockIdx.x;
    const int g    = bid >> 6;
    const int b    = (bid >> 4) & 3;
    const int tile = bid & 15;
    const int gy0  = tile * 4;
    const int p0   = tile * 256;

    const int tid  = threadIdx.x;
    const int wv   = tid >> 6;                // 0..7
    const int ln15 = tid & 15;
    const int quad = (tid & 63) >> 4;

    // ---- GEMM: wave wv owns n-cols p0+wv*32 (2 n-tiles) x 4 m-tiles ----
    f32x4 acc[8];
    #pragma unroll
    for (int i = 0; i < 8; ++i) acc[i] = (f32x4){0.f, 0.f, 0.f, 0.f};

    const char* bbase = (const char*)xp8 + (size_t)b * 32 * POCT * 16;
    const char* abase = (const char*)wbf + (size_t)g * KK_ * 512;

    int vb0, vb1;
    {
        int gi0 = p0 + wv * 32 + ln15;             // nt=0 pixel index
        int gi1 = gi0 + 16;                        // nt=1
        vb0 = (quad * POCT + ((gi0 >> 6) + 3) * PROW + 3 + (gi0 & 63)) * 16;
        vb1 = (quad * POCT + ((gi1 >> 6) + 3) * PROW + 3 + (gi1 & 63)) * 16;
    }
    int va  = ln15 * 512 + quad * 16;         // mt 0..2: + mt*8192 via s-base
    const int va3 = 48 * 512 + quad * 16;     // mt 3: row clamped to 48

    #pragma unroll
    for (int k = 0; k < 8; ++k) {
        bf16x8 af0 = *(const bf16x8*)(abase + va);
        bf16x8 af1 = *(const bf16x8*)(abase + 8192 + va);
        bf16x8 af2 = *(const bf16x8*)(abase + 16384 + va);
        bf16x8 af3 = *(const bf16x8*)(abase + va3 + k * 64);
        bf16x8 bf0 = *(const bf16x8*)(bbase + vb0);
        bf16x8 bf1 = *(const bf16x8*)(bbase + vb1);
        acc[0] = __builtin_amdgcn_mfma_f32_16x16x32_bf16(af0, bf0, acc[0], 0, 0, 0);
        acc[1] = __builtin_amdgcn_mfma_f32_16x16x32_bf16(af0, bf1, acc[1], 0, 0, 0);
        acc[2] = __builtin_amdgcn_mfma_f32_16x16x32_bf16(af1, bf0, acc[2], 0, 0, 0);
        acc[3] = __builtin_amdgcn_mfma_f32_16x16x32_bf16(af1, bf1, acc[3], 0, 0, 0);
        acc[4] = __builtin_amdgcn_mfma_f32_16x16x32_bf16(af2, bf0, acc[4], 0, 0, 0);
        acc[5] = __builtin_amdgcn_mfma_f32_16x16x32_bf16(af2, bf1, acc[5], 0, 0, 0);
        acc[6] = __builtin_amdgcn_mfma_f32_16x16x32_bf16(af3, bf0, acc[6], 0, 0, 0);
        acc[7] = __builtin_amdgcn_mfma_f32_16x16x32_bf16(af3, bf1, acc[7], 0, 0, 0);
        va  += 64;                              // +32 channels
        vb0 += 4 * POCT * 16; vb1 += 4 * POCT * 16;   // +4 octs
    }

    // ---- halo: branch-free global loads into regs (padding!), issued early ----
    // e in [0,1400): oct = e>=700, f = e - oct*700, row = gy0 + f/70, col = f%70
    #define HALO_LD(e_) ({                                                     \
        int e = (e_);                                                          \
        int o = (e >= 700) ? 1 : 0;                                            \
        int f = e - o * 700;                                                   \
        int r = f / 70;                                                        \
        int c = f - r * 70;                                                    \
        *(const uint4*)(bbase + ((size_t)(2 * g + o) * POCT                    \
                                 + (gy0 + r) * PROW + c) * 16); })
    uint4 h0 = HALO_LD(tid);
    uint4 h1 = HALO_LD(tid + 512);
    uint4 h2 = (tid < 376) ? HALO_LD(tid + 1024) : make_uint4(0u, 0u, 0u, 0u);

    // ---- epilogue: acc -> kernq[q7=mt*2+(quad>>1)][p], dword pair (quad&1)*2 ----
    #pragma unroll
    for (int mt = 0; mt < 3; ++mt) {                      // m <= 47
        const int m0 = mt * 16 + quad * 4;
        const float b0 = bk[g * KK_ + m0],     b1 = bk[g * KK_ + m0 + 1];
        const float b2 = bk[g * KK_ + m0 + 2], b3 = bk[g * KK_ + m0 + 3];
        const int q7 = mt * 2 + (quad >> 1);
        #pragma unroll
        for (int nt = 0; nt < 2; ++nt) {
            const int p = wv * 32 + nt * 16 + ln15;
            uint2 d;
            d.x = f2bf(acc[mt * 2 + nt][0] + b0) | (f2bf(acc[mt * 2 + nt][1] + b1) << 16);
            d.y = f2bf(acc[mt * 2 + nt][2] + b2) | (f2bf(acc[mt * 2 + nt][3] + b3) << 16);
            *(uint2*)&lds[(q7 * 256 + p) * 4 + (quad & 1) * 2] = d;
        }
    }
    if (quad == 0) {                                      // mt=3: only m=48 valid
        const float b48 = bk[g * KK_ + 48];
        #pragma unroll
        for (int nt = 0; nt < 2; ++nt) {
            const int p = wv * 32 + nt * 16 + ln15;
            lds[(6 * 256 + p) * 4] = f2bf(acc[6 + nt][0] + b48);   // lo=m48
        }
    }
    __syncthreads();   // barrier 1: kernq complete

    // ---- my pixel's 49 kern values: 7x conflict-free ds_read_b128 ----
    const int pix = tid & 255;
    const int ho  = tid >> 8;
    unsigned kd[28];
    #pragma unroll
    for (int q = 0; q < 7; ++q) {
        uint4 h = *(const uint4*)&lds[(q * 256 + pix) * 4];
        kd[4*q] = h.x; kd[4*q+1] = h.y; kd[4*q+2] = h.z; kd[4*q+3] = h.w;
    }
    __syncthreads();   // barrier 2: all kv reads done, LDS can be reused

    // ---- halo -> LDS (global loads have had the whole epilogue to land) ----
    *(uint4*)&lds[tid * 4] = h0;
    *(uint4*)&lds[(tid + 512) * 4] = h1;
    if (tid < 376) *(uint4*)&lds[(tid + 1024) * 4] = h2;
    __syncthreads();   // barrier 3: halo complete

    // ---- apply: taps from LDS, contiguous across lanes (conflict-free) ----
    const int py = pix >> 6, px = pix & 63;
    const int hbase = (ho * 700 + py * 70 + px) * 4;

    float a[8];
    #pragma unroll
    for (int q = 0; q < 8; ++q) a[q] = 0.f;
    #pragma unroll
    for (int kh = 0; kh < KS_; ++kh) {
        const uint4* hr = (const uint4*)&lds[hbase + kh * 280];
        #pragma unroll
        for (int kw = 0; kw < KS_; ++kw) {
            uint4 hv = hr[kw];
            const int t49 = kh * KS_ + kw;
            unsigned d = kd[t49 >> 1];
            float kk = __uint_as_float((t49 & 1) ? (d & 0xffff0000u) : (d << 16));
            a[0] = fmaf(__uint_as_float(hv.x << 16), kk, a[0]);
            a[1] = fmaf(__uint_as_float(hv.x),       kk, a[1]);
            a[2] = fmaf(__uint_as_float(hv.y << 16), kk, a[2]);
            a[3] = fmaf(__uint_as_float(hv.y),       kk, a[3]);
            a[4] = fmaf(__uint_as_float(hv.z << 16), kk, a[4]);
            a[5] = fmaf(__uint_as_float(hv.z),       kk, a[5]);
            a[6] = fmaf(__uint_as_float(hv.w << 16), kk, a[6]);
            a[7] = fmaf(__uint_as_float(hv.w),       kk, a[7]);
        }
    }
    const size_t o = ((size_t)(b * C_ + g * 16 + ho * 8) << 12) + p0 + pix;
    #pragma unroll
    for (int q = 0; q < 8; ++q)
        out[o + ((size_t)q << 12)] = a[q];
}

extern "C" void kernel_launch(void* const* d_in, const int* in_sizes, int n_in,
                              void* d_out, int out_size, void* d_ws, size_t ws_size,
                              hipStream_t stream) {
    const float* x  = (const float*)d_in[0];
    const float* wk = (const float*)d_in[1];
    const float* bk = (const float*)d_in[2];
    float* o = (float*)d_out;

    ushort_t* xp8 = (ushort_t*)d_ws;
    unsigned* wbf = (unsigned*)((char*)d_ws + WBF_OFF);

    cvt_xp8<<<dim3(66, 4, B_), dim3(256), 0, stream>>>(x, wk, xp8, wbf);
    inv_fused<<<dim3(1024), dim3(512), 0, stream>>>(
        xp8, (const ushort_t*)wbf, bk, o);
}